// Round 2
// baseline (10336.252 us; speedup 1.0000x reference)
//
#include <hip/hip_runtime.h>
#include <cstdint>
#include <cstddef>

#define S_LEN  2048
#define BATCH  2
#define NTOK   4096   // BATCH * S_LEN
#define DMODEL 1024   // NH * HDIM
#define NH     16
#define NKV    4
#define HDIM   64
#define KVDIM  256    // NKV * HDIM
#define FDIM   4096
#define NLAYER 2
#define VOCAB  32000

// ---------------- embed (gather) ----------------
__global__ __launch_bounds__(256) void k_embed(const int* __restrict__ idx,
                                               const float* __restrict__ emb,
                                               float* __restrict__ x) {
  int gid = blockIdx.x * 256 + threadIdx.x;   // NTOK*256 threads total
  int tok = gid >> 8, d4 = (gid & 255) * 4;
  int id = idx[tok];
  *(float4*)&x[(size_t)tok * DMODEL + d4] =
      *(const float4*)&emb[(size_t)id * DMODEL + d4];
}

// ---------------- rmsnorm ----------------
__global__ __launch_bounds__(256) void k_rmsnorm(const float* __restrict__ x,
                                                 const float* __restrict__ w,
                                                 float* __restrict__ out) {
  int row = blockIdx.x, tid = threadIdx.x;
  const float4 xv = *(const float4*)&x[(size_t)row * DMODEL + tid * 4];
  float ss = xv.x * xv.x + xv.y * xv.y + xv.z * xv.z + xv.w * xv.w;
#pragma unroll
  for (int off = 32; off; off >>= 1) ss += __shfl_xor(ss, off);
  __shared__ float red[4];
  if ((tid & 63) == 0) red[tid >> 6] = ss;
  __syncthreads();
  float tot = red[0] + red[1] + red[2] + red[3];
  float inv = 1.0f / sqrtf(tot * (1.0f / DMODEL) + 1e-5f);
  const float4 wv = *(const float4*)&w[tid * 4];
  float4 o;
  o.x = xv.x * inv * wv.x;
  o.y = xv.y * inv * wv.y;
  o.z = xv.z * inv * wv.z;
  o.w = xv.w * inv * wv.w;
  *(float4*)&out[(size_t)row * DMODEL + tid * 4] = o;
}

// ---------------- generic fp32 GEMM: C[M,N] = A[M,K] @ B[K,N] (+R) ----------------
// 64x64 tile, 256 threads, 4x4 per thread, K-step 16. LDS stride 68:
// float4 rows stay 16B-aligned and 68 % 32 == 4 breaks bank aliasing.
template <bool RESID>
__global__ __launch_bounds__(256) void k_gemm(const float* __restrict__ A,
                                              const float* __restrict__ B,
                                              float* __restrict__ C,
                                              const float* __restrict__ R,
                                              int M, int N, int K) {
  __shared__ float As[16][68];
  __shared__ float Bs[16][68];
  const int bn = blockIdx.x * 64, bm = blockIdx.y * 64;
  const int tid = threadIdx.x;
  const int tx = tid & 15, ty = tid >> 4;
  const int am = tid >> 2, ak = (tid & 3) * 4;
  const int bk = tid >> 4, bn4 = (tid & 15) * 4;
  const float* Aptr = A + (size_t)(bm + am) * K + ak;
  const float* Bptr = B + (size_t)bk * N + bn + bn4;
  float acc[4][4] = {};
  for (int k0 = 0; k0 < K; k0 += 16) {
    float4 av = *(const float4*)(Aptr + k0);
    float4 bv = *(const float4*)(Bptr + (size_t)k0 * N);
    __syncthreads();  // previous iteration's reads done before overwrite
    As[ak + 0][am] = av.x;
    As[ak + 1][am] = av.y;
    As[ak + 2][am] = av.z;
    As[ak + 3][am] = av.w;
    *(float4*)&Bs[bk][bn4] = bv;
    __syncthreads();
#pragma unroll
    for (int kk = 0; kk < 16; ++kk) {
      float4 a = *(const float4*)&As[kk][ty * 4];
      float4 b = *(const float4*)&Bs[kk][tx * 4];
      acc[0][0] = fmaf(a.x, b.x, acc[0][0]);
      acc[0][1] = fmaf(a.x, b.y, acc[0][1]);
      acc[0][2] = fmaf(a.x, b.z, acc[0][2]);
      acc[0][3] = fmaf(a.x, b.w, acc[0][3]);
      acc[1][0] = fmaf(a.y, b.x, acc[1][0]);
      acc[1][1] = fmaf(a.y, b.y, acc[1][1]);
      acc[1][2] = fmaf(a.y, b.z, acc[1][2]);
      acc[1][3] = fmaf(a.y, b.w, acc[1][3]);
      acc[2][0] = fmaf(a.z, b.x, acc[2][0]);
      acc[2][1] = fmaf(a.z, b.y, acc[2][1]);
      acc[2][2] = fmaf(a.z, b.z, acc[2][2]);
      acc[2][3] = fmaf(a.z, b.w, acc[2][3]);
      acc[3][0] = fmaf(a.w, b.x, acc[3][0]);
      acc[3][1] = fmaf(a.w, b.y, acc[3][1]);
      acc[3][2] = fmaf(a.w, b.z, acc[3][2]);
      acc[3][3] = fmaf(a.w, b.w, acc[3][3]);
    }
  }
#pragma unroll
  for (int i = 0; i < 4; ++i) {
    size_t off = (size_t)(bm + ty * 4 + i) * N + bn + tx * 4;
    float4 c;
    c.x = acc[i][0]; c.y = acc[i][1]; c.z = acc[i][2]; c.w = acc[i][3];
    if (RESID) {
      float4 r = *(const float4*)&R[off];
      c.x += r.x; c.y += r.y; c.z += r.z; c.w += r.w;
    }
    *(float4*)&C[off] = c;
  }
}

// ---------------- RoPE table (one-time, fp64 for exactness) ----------------
__global__ __launch_bounds__(256) void k_rope_table(float* __restrict__ cost,
                                                    float* __restrict__ sint) {
  int gid = blockIdx.x * 256 + threadIdx.x;  // S_LEN*32
  int t = gid >> 5, i = gid & 31;
  double inv = exp(-(double)i / 32.0 * log(500000.0));
  double f = (double)t * inv;
  cost[gid] = (float)cos(f);
  sint[gid] = (float)sin(f);
}

// ---------------- RoPE apply (rotate-half) ----------------
__global__ __launch_bounds__(256) void k_rope(float* __restrict__ x,
                                              const float* __restrict__ cost,
                                              const float* __restrict__ sint,
                                              int heads, int rowstride) {
  int gid = blockIdx.x * 256 + threadIdx.x;  // NTOK*heads*32
  int i = gid & 31;
  int h = (gid >> 5) % heads;
  int tok = gid / (heads * 32);
  int s = tok & (S_LEN - 1);
  float c = cost[s * 32 + i], sn = sint[s * 32 + i];
  float* p = x + (size_t)tok * rowstride + h * HDIM;
  float x0 = p[i], x1 = p[i + 32];
  p[i] = x0 * c - x1 * sn;        // out[:32] = x0*cos - x1*sin
  p[i + 32] = x1 * c + x0 * sn;   // out[32:] = x1*cos + x0*sin
}

// ---------------- flash-style attention ----------------
// grid: (S_LEN/4, NH, BATCH), block 256 = 4 waves; one wave per query row.
// K/V staged in LDS tiles of 64 keys (stride 65 breaks bank aliasing).
__global__ __launch_bounds__(256) void k_attn(const float* __restrict__ q,
                                              const float* __restrict__ k,
                                              const float* __restrict__ v,
                                              float* __restrict__ ctx) {
  __shared__ float Ks[64][65];
  __shared__ float Vs[64][65];
  __shared__ float Qs[4][64];
  __shared__ float Ps[4][64];
  const int qblk = blockIdx.x, h = blockIdx.y, b = blockIdx.z;
  const int kvh = h >> 2;  // REP = NH/NKV = 4
  const int tid = threadIdx.x;
  const int w = tid >> 6, lane = tid & 63;
  const int qi = qblk * 4 + w;
  const size_t qtok = (size_t)b * S_LEN + qi;
  Qs[w][lane] = q[qtok * DMODEL + h * HDIM + lane];
  float o = 0.f, m = -1e30f, l = 0.f;
  const int nt = (qblk * 4 + 3) / 64 + 1;  // block-uniform tile count
  for (int t = 0; t < nt; ++t) {
    __syncthreads();
#pragma unroll
    for (int r = 0; r < 16; ++r) {
      int idx = tid + r * 256;  // 0..4095
      int row = idx >> 6, col = idx & 63;
      size_t ktok = (size_t)b * S_LEN + t * 64 + row;
      Ks[row][col] = k[ktok * KVDIM + kvh * HDIM + col];
      Vs[row][col] = v[ktok * KVDIM + kvh * HDIM + col];
    }
    __syncthreads();
    float s = 0.f;
#pragma unroll
    for (int d = 0; d < 64; ++d) s = fmaf(Qs[w][d], Ks[lane][d], s);
    int key = t * 64 + lane;
    s = (key <= qi) ? s * 0.125f : -1e30f;  // SCALE = 1/sqrt(64)
    float mt = s;
#pragma unroll
    for (int off = 32; off; off >>= 1) mt = fmaxf(mt, __shfl_xor(mt, off));
    float mnew = fmaxf(m, mt);
    float p = expf(s - mnew);
    float scale = expf(m - mnew);
    float ps = p;
#pragma unroll
    for (int off = 32; off; off >>= 1) ps += __shfl_xor(ps, off);
    l = l * scale + ps;
    Ps[w][lane] = p;
    __syncthreads();
    float a = 0.f;
#pragma unroll
    for (int j = 0; j < 64; ++j) a = fmaf(Ps[w][j], Vs[j][lane], a);
    o = o * scale + a;
    m = mnew;
  }
  ctx[qtok * DMODEL + h * HDIM + lane] = o / l;
}

// ---------------- silu(g) * u, in place into g ----------------
__global__ __launch_bounds__(256) void k_silu_mul(float* __restrict__ g,
                                                  const float* __restrict__ u) {
  size_t gid = (size_t)(blockIdx.x * 256 + threadIdx.x) * 4;
  float4 gv = *(float4*)&g[gid];
  float4 uv = *(const float4*)&u[gid];
  gv.x = gv.x / (1.f + expf(-gv.x)) * uv.x;
  gv.y = gv.y / (1.f + expf(-gv.y)) * uv.y;
  gv.z = gv.z / (1.f + expf(-gv.z)) * uv.z;
  gv.w = gv.w / (1.f + expf(-gv.w)) * uv.w;
  *(float4*)&g[gid] = gv;
}

extern "C" void kernel_launch(void* const* d_in, const int* in_sizes, int n_in,
                              void* d_out, int out_size, void* d_ws, size_t ws_size,
                              hipStream_t stream) {
  const int* in_idx = (const int*)d_in[0];
  const float* token_emb = (const float*)d_in[1];
  const float* wq = (const float*)d_in[2];
  const float* wk = (const float*)d_in[3];
  const float* wv = (const float*)d_in[4];
  const float* wo = (const float*)d_in[5];
  const float* w_gate = (const float*)d_in[6];
  const float* w_up = (const float*)d_in[7];
  const float* w_down = (const float*)d_in[8];
  const float* norm_attn = (const float*)d_in[9];
  const float* norm_ff = (const float*)d_in[10];
  const float* norm_final = (const float*)d_in[11];
  const float* w_out = (const float*)d_in[12];
  float* out = (float*)d_out;

  float* ws = (float*)d_ws;
  float* x = ws;    ws += (size_t)NTOK * DMODEL;
  float* n = ws;    ws += (size_t)NTOK * DMODEL;
  float* q = ws;    ws += (size_t)NTOK * DMODEL;
  float* kb = ws;   ws += (size_t)NTOK * KVDIM;
  float* vb = ws;   ws += (size_t)NTOK * KVDIM;
  float* ctx = ws;  ws += (size_t)NTOK * DMODEL;
  float* g = ws;    ws += (size_t)NTOK * FDIM;
  float* u = ws;    ws += (size_t)NTOK * FDIM;
  float* cost = ws; ws += S_LEN * 32;
  float* sint = ws; ws += S_LEN * 32;

  dim3 blk(256);
  k_rope_table<<<S_LEN * 32 / 256, blk, 0, stream>>>(cost, sint);
  k_embed<<<NTOK, blk, 0, stream>>>(in_idx, token_emb, x);

  for (int l = 0; l < NLAYER; ++l) {
    k_rmsnorm<<<NTOK, blk, 0, stream>>>(x, norm_attn + (size_t)l * DMODEL, n);
    k_gemm<false><<<dim3(DMODEL / 64, NTOK / 64), blk, 0, stream>>>(
        n, wq + (size_t)l * DMODEL * DMODEL, q, nullptr, NTOK, DMODEL, DMODEL);
    k_gemm<false><<<dim3(KVDIM / 64, NTOK / 64), blk, 0, stream>>>(
        n, wk + (size_t)l * DMODEL * KVDIM, kb, nullptr, NTOK, KVDIM, DMODEL);
    k_gemm<false><<<dim3(KVDIM / 64, NTOK / 64), blk, 0, stream>>>(
        n, wv + (size_t)l * DMODEL * KVDIM, vb, nullptr, NTOK, KVDIM, DMODEL);
    k_rope<<<NTOK * NH * 32 / 256, blk, 0, stream>>>(q, cost, sint, NH, DMODEL);
    k_rope<<<NTOK * NKV * 32 / 256, blk, 0, stream>>>(kb, cost, sint, NKV, KVDIM);
    k_attn<<<dim3(S_LEN / 4, NH, BATCH), blk, 0, stream>>>(q, kb, vb, ctx);
    k_gemm<true><<<dim3(DMODEL / 64, NTOK / 64), blk, 0, stream>>>(
        ctx, wo + (size_t)l * DMODEL * DMODEL, x, x, NTOK, DMODEL, DMODEL);
    k_rmsnorm<<<NTOK, blk, 0, stream>>>(x, norm_ff + (size_t)l * DMODEL, n);
    k_gemm<false><<<dim3(FDIM / 64, NTOK / 64), blk, 0, stream>>>(
        n, w_gate + (size_t)l * DMODEL * FDIM, g, nullptr, NTOK, FDIM, DMODEL);
    k_gemm<false><<<dim3(FDIM / 64, NTOK / 64), blk, 0, stream>>>(
        n, w_up + (size_t)l * DMODEL * FDIM, u, nullptr, NTOK, FDIM, DMODEL);
    k_silu_mul<<<(NTOK * (FDIM / 4)) / 256, blk, 0, stream>>>(g, u);
    k_gemm<true><<<dim3(DMODEL / 64, NTOK / 64), blk, 0, stream>>>(
        g, w_down + (size_t)l * FDIM * DMODEL, x, x, NTOK, DMODEL, FDIM);
  }
  k_rmsnorm<<<NTOK, blk, 0, stream>>>(x, norm_final, n);
  k_gemm<false><<<dim3(VOCAB / 64, NTOK / 64), blk, 0, stream>>>(
      n, w_out, out, nullptr, NTOK, VOCAB, DMODEL);
}